// Round 17
// baseline (713.042 us; speedup 1.0000x reference)
//
#include <hip/hip_runtime.h>
#include <hip/hip_bf16.h>
#include <math.h>

typedef __bf16 bf16_t;
typedef __bf16 bf16x4 __attribute__((ext_vector_type(4)));
typedef __bf16 bf16x8 __attribute__((ext_vector_type(8)));
typedef float f32x4 __attribute__((ext_vector_type(4)));

#define TB 2048
#define BB 2
#define EE 768
#define HH 12
#define MM (BB * TB)   // 4096 rows
#define E3 (3 * EE)    // 2304
#define E4 (4 * EE)    // 3072

// compile-time for: gives the body a true constexpr index.
template <int V> struct ICst { static constexpr int value = V; };
template <int N, int I = 0, typename F>
__device__ __forceinline__ void static_for(F&& f) {
  if constexpr (I < N) {
    f(ICst<I>{});
    static_for<N, I + 1>(f);
  }
}

// ---------------- prep: weight transposes (+bf16), LayerNorm1, counter zeroing.
// wq pre-scaled by 1/sqrt(D)=0.125 (exact).
// id 2752: zero split-K merge counters (ws is 0xAA-poisoned each call).
__global__ __launch_bounds__(256) void k_prep(
    const float* __restrict__ wq, const float* __restrict__ wk,
    const float* __restrict__ wv, const float* __restrict__ wo,
    const float* __restrict__ w1, const float* __restrict__ w2,
    bf16_t* __restrict__ wqkvT, bf16_t* __restrict__ woT,
    bf16_t* __restrict__ w1T, bf16_t* __restrict__ w2T,
    const float* __restrict__ x, const float* __restrict__ ln1s,
    const float* __restrict__ ln1b, bf16_t* __restrict__ hbf,
    int* __restrict__ cnt) {
  __shared__ bf16_t tile[64][72];
  int id = blockIdx.x;
  int tid = threadIdx.x;
  if (id == 2752) {  // ---- counter zero path
    for (int i = tid; i < 1024; i += 256) cnt[i] = 0;
    return;
  }
  if (id >= 1728) {  // ---- LN1 path
    int wave = tid >> 6, lane = tid & 63;
    int row = (id - 1728) * 4 + wave;
    const float* xr = x + (size_t)row * EE;
    float v[12];
    float s = 0.f, sq = 0.f;
#pragma unroll
    for (int i = 0; i < 12; i++) {
      float t = xr[lane + 64 * i];
      v[i] = t; s += t; sq += t * t;
    }
#pragma unroll
    for (int off = 1; off < 64; off <<= 1) {
      s += __shfl_xor(s, off);
      sq += __shfl_xor(sq, off);
    }
    float mean = s * (1.f / EE);
    float var = (sq - (float)EE * mean * mean) * (1.f / (EE - 1));
    float rstd = rsqrtf(var + 1e-5f);
    bf16_t* orow = hbf + (size_t)row * EE;
#pragma unroll
    for (int i = 0; i < 12; i++) {
      int e = lane + 64 * i;
      orow[e] = (bf16_t)(ln1s[e] * (v[i] - mean) * rstd + ln1b[e]);
    }
    return;
  }
  // ---- transpose path
  const float* src;
  bf16_t* dst;
  int K, N, kt, nt;
  float scl = 1.f;
  if (id < 576) {
    int m = id / 144, t = id - m * 144;
    kt = (t / 12) * 64; nt = (t % 12) * 64; K = 768; N = 768;
    src = (m == 0) ? wq : (m == 1) ? wk : (m == 2) ? wv : wo;
    dst = (m < 3) ? wqkvT + (size_t)m * 768 * 768 : woT;
    if (m == 0) scl = 0.125f;
  } else if (id < 1152) {
    int t = id - 576;
    kt = (t / 48) * 64; nt = (t % 48) * 64; K = 768; N = 3072;
    src = w1; dst = w1T;
  } else {
    int t = id - 1152;
    kt = (t / 12) * 64; nt = (t % 12) * 64; K = 3072; N = 768;
    src = w2; dst = w2T;
  }
  int r = tid >> 2, c = (tid & 3) * 16;
  const float* s = src + (size_t)(kt + r) * N + nt + c;
  bf16x8 t0, t1;
#pragma unroll
  for (int j = 0; j < 8; j++) {
    t0[j] = (bf16_t)(s[j] * scl);
    t1[j] = (bf16_t)(s[8 + j] * scl);
  }
  *(bf16x8*)&tile[r][c] = t0;
  *(bf16x8*)&tile[r][c + 8] = t1;
  __syncthreads();
  bf16_t* d = dst + (size_t)(nt + r) * K + kt + c;
  bf16x8 o0, o1;
#pragma unroll
  for (int j = 0; j < 8; j++) { o0[j] = tile[c + j][r]; o1[j] = tile[c + 8 + j][r]; }
  *(bf16x8*)d = o0;
  *(bf16x8*)(d + 8) = o1;
}

// ---------------- 128x128 bf16 MFMA GEMM, BK=64, XOR-swizzled LDS.
// NITER templated (R13): fully unrolled K-loop; builtin offset stays 0 (R12).
// epi: 0 bf16 (V-tiles of QKV redirected transposed into vtout);
//      1 bias+GELU bf16; 2 bias+resid fp32; 3 bf16 partial +z*M*N;
//      4 bf16 partial + LAST-BLOCK MERGE (4 splits) + bias + resid -> outf.
template <int NITER>
__global__ __launch_bounds__(256) void k_gemm128(
    const bf16_t* __restrict__ A, const bf16_t* __restrict__ Bt,
    int M, int N, int K, int epi,
    float* __restrict__ outf, bf16_t* __restrict__ outb,
    const float* __restrict__ bias, const float* __restrict__ resid,
    bf16_t* __restrict__ vtout, int* __restrict__ cnt) {
  __shared__ bf16_t As[128 * 64];
  __shared__ bf16_t Bs[128 * 64];
  int tid = threadIdx.x;
  int wave = tid >> 6, lane = tid & 63;
  int m0 = blockIdx.y * 128, n0 = blockIdx.x * 128;
  int kOff = blockIdx.z * (NITER * 64);
  int wm = (wave >> 1) * 64, wn = (wave & 1) * 64;
  int lm = lane & 15, quad = lane >> 4;

  int srow = wave * 32 + (lane >> 3);
  int scol = (((lane & 7) ^ ((lane >> 3) & 7)) * 8);
  const bf16_t* Ap[4];
  const bf16_t* Bp[4];
  bf16_t* ldsA[4];
  bf16_t* ldsB[4];
#pragma unroll
  for (int j = 0; j < 4; j++) {
    Ap[j] = A + (size_t)(m0 + srow) * K + kOff + scol + (size_t)j * 8 * K;
    Bp[j] = Bt + (size_t)(n0 + srow) * K + kOff + scol + (size_t)j * 8 * K;
    ldsA[j] = &As[(wave * 32 + j * 8) * 64];
    ldsB[j] = &Bs[(wave * 32 + j * 8) * 64];
  }

  int aOff[2][4], bOff[2][4];
#pragma unroll
  for (int c = 0; c < 2; c++) {
    int g = ((c * 4 + quad) ^ (lm & 7)) * 8;
#pragma unroll
    for (int i = 0; i < 4; i++) {
      aOff[c][i] = (wm + i * 16 + lm) * 64 + g;
      bOff[c][i] = (wn + i * 16 + lm) * 64 + g;
    }
  }

  f32x4 acc[4][4];
#pragma unroll
  for (int i = 0; i < 4; i++)
#pragma unroll
    for (int j = 0; j < 4; j++) acc[i][j] = (f32x4){0.f, 0.f, 0.f, 0.f};

  static_for<NITER>([&](auto kc) {
    constexpr int k = decltype(kc)::value;
    __syncthreads();
#pragma unroll
    for (int j = 0; j < 4; j++) {
      __builtin_amdgcn_global_load_lds(
          (const __attribute__((address_space(1))) void*)(Ap[j] + k * 64),
          (__attribute__((address_space(3))) void*)ldsA[j], 16, 0, 0);
      __builtin_amdgcn_global_load_lds(
          (const __attribute__((address_space(1))) void*)(Bp[j] + k * 64),
          (__attribute__((address_space(3))) void*)ldsB[j], 16, 0, 0);
    }
    __syncthreads();
#pragma unroll
    for (int c = 0; c < 2; c++) {
      bf16x8 af[4], bfr[4];
#pragma unroll
      for (int i = 0; i < 4; i++) {
        af[i] = *(const bf16x8*)&As[aOff[c][i]];
        bfr[i] = *(const bf16x8*)&Bs[bOff[c][i]];
      }
#pragma unroll
      for (int i = 0; i < 4; i++)
#pragma unroll
        for (int j = 0; j < 4; j++)
          acc[i][j] = __builtin_amdgcn_mfma_f32_16x16x32_bf16(af[i], bfr[j], acc[i][j], 0, 0, 0);
    }
  });

  size_t pbase = (size_t)blockIdx.z * M * N;
  bool vtile = (epi == 0) && (n0 >= 2 * EE);
#pragma unroll
  for (int i = 0; i < 4; i++) {
#pragma unroll
    for (int j = 0; j < 4; j++) {
      int col = n0 + wn + j * 16 + lm;
      if (vtile) {
        int hv = (col - 2 * EE) >> 6, d = (col - 2 * EE) & 63;
        int row0 = m0 + wm + i * 16 + quad * 4;
        int bb = row0 >> 11, t0 = row0 & (TB - 1);
        bf16x4 v4;
#pragma unroll
        for (int r = 0; r < 4; r++) v4[r] = (bf16_t)acc[i][j][r];
        *(bf16x4*)&vtout[((size_t)(bb * HH + hv) * 64 + d) * TB + t0] = v4;
        continue;
      }
#pragma unroll
      for (int r = 0; r < 4; r++) {
        int row = m0 + wm + i * 16 + quad * 4 + r;
        size_t o = (size_t)row * N + col;
        float c = acc[i][j][r];
        if (epi == 0) {
          outb[o] = (bf16_t)c;
        } else if (epi == 1) {
          float xg = c + bias[col];
          float u2 = xg * 1.5957691216057308f + xg * xg * xg * 0.07135481627561393f;
          float t = 1.f - 2.f / (__expf(u2) + 1.f);  // tanh(u2/2), inf-safe
          outb[o] = (bf16_t)(0.5f * xg * (1.f + t));
        } else if (epi == 2) {
          outf[o] = c + bias[col] + resid[o];
        } else {
          outb[pbase + o] = (bf16_t)c;
        }
      }
    }
  }

  if (epi == 4) {  // self-merging split-K (4 splits): last block per tile merges
    __threadfence();   // release this thread's partial stores (device scope)
    __syncthreads();   // all threads' fences complete
    __shared__ int lastFlag;
    if (tid == 0)
      lastFlag = (atomicAdd(&cnt[768 + blockIdx.y * gridDim.x + blockIdx.x], 1) == 3);
    __syncthreads();
    if (lastFlag) {
      __threadfence();  // acquire: see other splits' stores
      int r = tid >> 1;
      int cb = (tid & 1) * 64;
      int colb = n0 + cb;
      size_t rowoff = (size_t)(m0 + r) * N + colb;
#pragma unroll
      for (int ch = 0; ch < 8; ch++) {
        size_t o = rowoff + ch * 8;
        bf16x8 p0 = *(const bf16x8*)&outb[o];
        bf16x8 p1 = *(const bf16x8*)&outb[(size_t)M * N + o];
        bf16x8 p2 = *(const bf16x8*)&outb[(size_t)2 * M * N + o];
        bf16x8 p3 = *(const bf16x8*)&outb[(size_t)3 * M * N + o];
#pragma unroll
        for (int e = 0; e < 8; e++)
          outf[o + e] = (float)p0[e] + (float)p1[e] + (float)p2[e] + (float)p3[e] +
                        bias[colb + ch * 8 + e] + resid[o + e];
      }
    }
  }
}

// ---------------- attn-out reduce (2 partials) + bias + resid -> x1, fused LN2 -> h2
__global__ __launch_bounds__(256) void k_reduce_ln2(
    const bf16_t* __restrict__ p, const float* __restrict__ bo_,
    const float* __restrict__ x, const float* __restrict__ sc,
    const float* __restrict__ sh, float* __restrict__ x1,
    bf16_t* __restrict__ h2) {
  int wave = threadIdx.x >> 6, lane = threadIdx.x & 63;
  int row = blockIdx.x * 4 + wave;
  const bf16_t* p0 = p + (size_t)row * EE;
  const bf16_t* p1 = p0 + (size_t)MM * EE;
  const float* xr = x + (size_t)row * EE;
  float v[12];
  float s = 0.f, sq = 0.f;
#pragma unroll
  for (int i = 0; i < 12; i++) {
    int e = lane + 64 * i;
    float t = (float)p0[e] + (float)p1[e] + bo_[e] + xr[e];
    v[i] = t; s += t; sq += t * t;
  }
#pragma unroll
  for (int off = 1; off < 64; off <<= 1) {
    s += __shfl_xor(s, off);
    sq += __shfl_xor(sq, off);
  }
  float mean = s * (1.f / EE);
  float var = (sq - (float)EE * mean * mean) * (1.f / (EE - 1));
  float rstd = rsqrtf(var + 1e-5f);
  float* x1r = x1 + (size_t)row * EE;
  bf16_t* h2r = h2 + (size_t)row * EE;
#pragma unroll
  for (int i = 0; i < 12; i++) {
    int e = lane + 64 * i;
    x1r[e] = v[i];
    h2r[e] = (bf16_t)(sc[e] * (v[i] - mean) * rstd + sh[e]);
  }
}

// ---------------- MFMA flash attention, causal, NO-MAX softmax, kv-split,
// SELF-MERGING: nsplit==1 blocks write ctx directly; otherwise the last chunk
// per (bh,qt) merges all partials in-kernel (device-scope fence + counter).
__global__ __launch_bounds__(256) void k_attn_mfma(const bf16_t* __restrict__ qkv,
                                                   const bf16_t* __restrict__ vt,
                                                   bf16_t* __restrict__ opart,
                                                   float* __restrict__ lpart,
                                                   bf16_t* __restrict__ ctx,
                                                   int* __restrict__ cnt) {
  __shared__ bf16_t Qs[64][72];
  __shared__ bf16_t Ks[64][72];
  __shared__ bf16_t Vt[64][72];
  __shared__ bf16_t Ps[4][16][72];

  int bh = blockIdx.x;
  int y = blockIdx.y;
  int qt, c, nsplit;
  if (y < 32)      { qt = 24 + (y >> 2); c = y & 3; nsplit = 4; }
  else if (y < 56) { int z = y - 32; qt = 16 + z / 3; c = z - (z / 3) * 3; nsplit = 3; }
  else if (y < 72) { int z = y - 56; qt = 8 + (z >> 1); c = z & 1; nsplit = 2; }
  else             { qt = y - 72; c = 0; nsplit = 1; }
  int ntiles = qt + 1;
  int len = (ntiles + nsplit - 1) / nsplit;
  int k0t = c * len;
  int k1t = k0t + len < ntiles ? k0t + len : ntiles;

  int b = bh / HH, h = bh - b * HH;
  int q0 = qt * 64;
  int tid = threadIdx.x;
  int wave = tid >> 6, lane = tid & 63;
  int lm = lane & 15, quad = lane >> 4;
  int sr = tid >> 2, sc = (tid & 3) * 16;
  const bf16_t* vt_bh = vt + (size_t)bh * 64 * TB;

  {
    const bf16_t* src = qkv + (size_t)(b * TB + q0 + sr) * E3 + h * 64 + sc;
    *(bf16x8*)(&Qs[sr][sc]) = *(const bf16x8*)src;
    *(bf16x8*)(&Qs[sr][sc + 8]) = *(const bf16x8*)(src + 8);
  }
  __syncthreads();
  bf16x8 qf0 = *(const bf16x8*)(&Qs[wave * 16 + lm][quad * 8]);
  bf16x8 qf1 = *(const bf16x8*)(&Qs[wave * 16 + lm][32 + quad * 8]);

  f32x4 o_acc[4];
#pragma unroll
  for (int nt = 0; nt < 4; nt++) o_acc[nt] = (f32x4){0.f, 0.f, 0.f, 0.f};
  float l = 0.f;

  for (int kt = k0t; kt < k1t; kt++) {
    __syncthreads();
    {
      const bf16_t* ksrc = qkv + (size_t)(b * TB + kt * 64 + sr) * E3 + EE + h * 64 + sc;
      *(bf16x8*)(&Ks[sr][sc]) = *(const bf16x8*)ksrc;
      *(bf16x8*)(&Ks[sr][sc + 8]) = *(const bf16x8*)(ksrc + 8);
      const bf16_t* vsrc = vt_bh + (size_t)sr * TB + kt * 64 + sc;
      *(bf16x8*)(&Vt[sr][sc]) = *(const bf16x8*)vsrc;
      *(bf16x8*)(&Vt[sr][sc + 8]) = *(const bf16x8*)(vsrc + 8);
    }
    __syncthreads();

    f32x4 st[4];
#pragma unroll
    for (int nt = 0; nt < 4; nt++) {
      st[nt] = (f32x4){0.f, 0.f, 0.f, 0.f};
      bf16x8 kf0 = *(const bf16x8*)(&Ks[nt * 16 + lm][quad * 8]);
      bf16x8 kf1 = *(const bf16x8*)(&Ks[nt * 16 + lm][32 + quad * 8]);
      st[nt] = __builtin_amdgcn_mfma_f32_16x16x32_bf16(kf0, qf0, st[nt], 0, 0, 0);
      st[nt] = __builtin_amdgcn_mfma_f32_16x16x32_bf16(kf1, qf1, st[nt], 0, 0, 0);
    }
    if (kt == qt) {
#pragma unroll
      for (int nt = 0; nt < 4; nt++)
#pragma unroll
        for (int r = 0; r < 4; r++)
          if (nt * 16 + quad * 4 + r > wave * 16 + lm) st[nt][r] = -1e30f;
    }

#pragma unroll
    for (int nt = 0; nt < 4; nt++) {
      bf16x4 pk;
#pragma unroll
      for (int r = 0; r < 4; r++) {
        float p = __expf(st[nt][r]);
        pk[r] = (bf16_t)p;
        l += p;
      }
      *(bf16x4*)(&Ps[wave][lm][nt * 16 + quad * 4]) = pk;
    }

    bf16x8 pf0 = *(const bf16x8*)(&Ps[wave][lm][quad * 8]);
    bf16x8 pf1 = *(const bf16x8*)(&Ps[wave][lm][32 + quad * 8]);
#pragma unroll
    for (int nt = 0; nt < 4; nt++) {
      bf16x8 vf0 = *(const bf16x8*)(&Vt[nt * 16 + lm][quad * 8]);
      bf16x8 vf1 = *(const bf16x8*)(&Vt[nt * 16 + lm][32 + quad * 8]);
      o_acc[nt] = __builtin_amdgcn_mfma_f32_16x16x32_bf16(pf0, vf0, o_acc[nt], 0, 0, 0);
      o_acc[nt] = __builtin_amdgcn_mfma_f32_16x16x32_bf16(pf1, vf1, o_acc[nt], 0, 0, 0);
    }
  }

  l += __shfl_xor(l, 16);
  l += __shfl_xor(l, 32);

  if (nsplit == 1) {  // qt<8: write ctx directly, no partials/counter
    float inv = 1.f / l;
    float inv_c[4];
#pragma unroll
    for (int r = 0; r < 4; r++) inv_c[r] = __shfl(inv, quad * 4 + r);
#pragma unroll
    for (int nt = 0; nt < 4; nt++)
#pragma unroll
      for (int r = 0; r < 4; r++) {
        int row = q0 + wave * 16 + quad * 4 + r;
        ctx[(size_t)(b * TB + row) * EE + h * 64 + nt * 16 + lm] =
            (bf16_t)(o_acc[nt][r] * inv_c[r]);
      }
    return;
  }

  size_t slot = (size_t)(bh * 32 + qt) * 4 + c;
  if (quad == 0) lpart[slot * 64 + wave * 16 + lm] = l;
  bf16_t* ob = opart + slot * 4096;
#pragma unroll
  for (int nt = 0; nt < 4; nt++)
#pragma unroll
    for (int r = 0; r < 4; r++)
      ob[(wave * 16 + quad * 4 + r) * 64 + nt * 16 + lm] = (bf16_t)o_acc[nt][r];

  // last-chunk merge (replaces k_attn_reduce dispatch)
  __threadfence();   // release partial stores
  __syncthreads();
  __shared__ int lastFlag;
  if (tid == 0)
    lastFlag = (atomicAdd(&cnt[bh * 32 + qt], 1) == nsplit - 1);
  __syncthreads();
  if (lastFlag) {
    __threadfence();  // acquire other chunks' stores
    int q = tid >> 2, dc = (tid & 3) * 16;
    size_t slot0 = (size_t)(bh * 32 + qt) * 4;
    float o[16];
#pragma unroll
    for (int j = 0; j < 16; j++) o[j] = 0.f;
    float lsum = 0.f;
    for (int cc = 0; cc < nsplit; cc++) {
      const bf16_t* p = opart + (slot0 + cc) * 4096 + q * 64 + dc;
      bf16x8 u0 = *(const bf16x8*)p;
      bf16x8 u1 = *(const bf16x8*)(p + 8);
#pragma unroll
      for (int j = 0; j < 8; j++) { o[j] += (float)u0[j]; o[8 + j] += (float)u1[j]; }
      lsum += lpart[(slot0 + cc) * 64 + q];
    }
    float inv = 1.f / lsum;
    bf16_t* dst = ctx + (size_t)(b * TB + qt * 64 + q) * EE + h * 64 + dc;
    bf16x8 d0, d1;
#pragma unroll
    for (int j = 0; j < 8; j++) {
      d0[j] = (bf16_t)(o[j] * inv);
      d1[j] = (bf16_t)(o[8 + j] * inv);
    }
    *(bf16x8*)dst = d0;
    *(bf16x8*)(dst + 8) = d1;
  }
}

extern "C" void kernel_launch(void* const* d_in, const int* in_sizes, int n_in,
                              void* d_out, int out_size, void* d_ws, size_t ws_size,
                              hipStream_t stream) {
  const float* x    = (const float*)d_in[0];
  const float* wq   = (const float*)d_in[1];
  const float* wk   = (const float*)d_in[2];
  const float* wv   = (const float*)d_in[3];
  const float* wo   = (const float*)d_in[4];
  const float* bo   = (const float*)d_in[5];
  const float* ln1s = (const float*)d_in[6];
  const float* ln1b = (const float*)d_in[7];
  const float* ln2s = (const float*)d_in[8];
  const float* ln2b = (const float*)d_in[9];
  const float* w1   = (const float*)d_in[10];
  const float* b1   = (const float*)d_in[11];
  const float* w2   = (const float*)d_in[12];
  const float* b2   = (const float*)d_in[13];
  float* out = (float*)d_out;

  char* ws = (char*)d_ws;
  size_t off = 0;
  auto alloc = [&](size_t bytes) {
    char* p = ws + off;
    off += (bytes + 255) & ~(size_t)255;
    return p;
  };
  float*  x1    = (float*) alloc((size_t)MM * EE * 4);   // post-attn residual
  bf16_t* w1T   = (bf16_t*)alloc((size_t)E4 * EE * 2);
  bf16_t* w2T   = (bf16_t*)alloc((size_t)EE * E4 * 2);
  bf16_t* woT   = (bf16_t*)alloc((size_t)EE * EE * 2);
  bf16_t* wqkvT = (bf16_t*)alloc((size_t)E3 * EE * 2);
  bf16_t* hbf   = (bf16_t*)alloc((size_t)MM * EE * 2);   // ln1 out; reused as ctx
  bf16_t* h2    = (bf16_t*)alloc((size_t)MM * EE * 2);   // ln2 out
  bf16_t* vtb   = (bf16_t*)alloc((size_t)BB * HH * 64 * TB * 2);  // V^T
  bf16_t* part  = (bf16_t*)alloc((size_t)4 * MM * EE * 2);        // split-K partials
  bf16_t* opart = (bf16_t*)alloc((size_t)BB * HH * 32 * 4 * 4096 * 2);  // attn O partials
  float*  lpart = (float*) alloc((size_t)BB * HH * 32 * 4 * 64 * 4);    // attn l partials
  int*    cnt   = (int*)   alloc(1024 * 4);               // merge counters
  bf16_t* qkv   = (bf16_t*)alloc((size_t)MM * E3 * 2);   // LAST: hmid overlays +6.3MB
  bf16_t* hmid  = qkv;  // MLP mid (4096 x 3072)

  // weight transposes + LN1 + counter zeroing in one dispatch
  k_prep<<<2753, 256, 0, stream>>>(wq, wk, wv, wo, w1, w2,
                                   wqkvT, woT, w1T, w2T, x, ln1s, ln1b, hbf, cnt);
  // fused QKV projection (K=768 -> 12 iters); V-tiles written transposed into vtb
  k_gemm128<12><<<dim3(E3 / 128, MM / 128), 256, 0, stream>>>(
      hbf, wqkvT, MM, E3, EE, 0, nullptr, qkv, nullptr, nullptr, vtb, nullptr);
  // attention: kv-split, SELF-MERGING -> ctx (k_attn_reduce deleted)
  k_attn_mfma<<<dim3(BB * HH, 80), 256, 0, stream>>>(qkv, vtb, opart, lpart, hbf, cnt);
  // output projection: split-K x2 (kLen=384 -> 6 iters) -> bf16 partials
  k_gemm128<6><<<dim3(EE / 128, MM / 128, 2), 256, 0, stream>>>(
      hbf, woT, MM, EE, EE, 3, nullptr, part, nullptr, nullptr, nullptr, nullptr);
  // reduce 2 partials + bias + resid -> x1, fused LN2 -> h2
  k_reduce_ln2<<<MM / 4, 256, 0, stream>>>(part, bo, x, ln2s, ln2b, x1, h2);
  // MLP1 + bias + gelu (K=768 -> 12 iters)
  k_gemm128<12><<<dim3(E4 / 128, MM / 128), 256, 0, stream>>>(
      h2, w1T, MM, E4, EE, 1, nullptr, hmid, b1, nullptr, nullptr, nullptr);
  // MLP2: split-K x4, SELF-MERGING + bias + resid -> out (k_reduce_out deleted)
  k_gemm128<12><<<dim3(EE / 128, MM / 128, 4), 256, 0, stream>>>(
      hmid, w2T, MM, EE, E4, 4, out, part, b2, x1, nullptr, cnt);
}

// Round 18
// 276.071 us; speedup vs baseline: 2.5828x; 2.5828x over previous
//
#include <hip/hip_runtime.h>
#include <hip/hip_bf16.h>
#include <math.h>

typedef __bf16 bf16_t;
typedef __bf16 bf16x4 __attribute__((ext_vector_type(4)));
typedef __bf16 bf16x8 __attribute__((ext_vector_type(8)));
typedef float f32x4 __attribute__((ext_vector_type(4)));

#define TB 2048
#define BB 2
#define EE 768
#define HH 12
#define MM (BB * TB)   // 4096 rows
#define E3 (3 * EE)    // 2304
#define E4 (4 * EE)    // 3072

// compile-time for: gives the body a true constexpr index.
template <int V> struct ICst { static constexpr int value = V; };
template <int N, int I = 0, typename F>
__device__ __forceinline__ void static_for(F&& f) {
  if constexpr (I < N) {
    f(ICst<I>{});
    static_for<N, I + 1>(f);
  }
}

// ---------------- prep: ALL weight transposes (+bf16 cast) AND LayerNorm1.
// wq pre-scaled by 1/sqrt(D)=0.125 (exact) so attention needs no Q-scaling.
__global__ __launch_bounds__(256) void k_prep(
    const float* __restrict__ wq, const float* __restrict__ wk,
    const float* __restrict__ wv, const float* __restrict__ wo,
    const float* __restrict__ w1, const float* __restrict__ w2,
    bf16_t* __restrict__ wqkvT, bf16_t* __restrict__ woT,
    bf16_t* __restrict__ w1T, bf16_t* __restrict__ w2T,
    const float* __restrict__ x, const float* __restrict__ ln1s,
    const float* __restrict__ ln1b, bf16_t* __restrict__ hbf) {
  __shared__ bf16_t tile[64][72];
  int id = blockIdx.x;
  int tid = threadIdx.x;
  if (id >= 1728) {  // ---- LN1 path
    int wave = tid >> 6, lane = tid & 63;
    int row = (id - 1728) * 4 + wave;
    const float* xr = x + (size_t)row * EE;
    float v[12];
    float s = 0.f, sq = 0.f;
#pragma unroll
    for (int i = 0; i < 12; i++) {
      float t = xr[lane + 64 * i];
      v[i] = t; s += t; sq += t * t;
    }
#pragma unroll
    for (int off = 1; off < 64; off <<= 1) {
      s += __shfl_xor(s, off);
      sq += __shfl_xor(sq, off);
    }
    float mean = s * (1.f / EE);
    float var = (sq - (float)EE * mean * mean) * (1.f / (EE - 1));
    float rstd = rsqrtf(var + 1e-5f);
    bf16_t* orow = hbf + (size_t)row * EE;
#pragma unroll
    for (int i = 0; i < 12; i++) {
      int e = lane + 64 * i;
      orow[e] = (bf16_t)(ln1s[e] * (v[i] - mean) * rstd + ln1b[e]);
    }
    return;
  }
  // ---- transpose path
  const float* src;
  bf16_t* dst;
  int K, N, kt, nt;
  float scl = 1.f;
  if (id < 576) {
    int m = id / 144, t = id - m * 144;
    kt = (t / 12) * 64; nt = (t % 12) * 64; K = 768; N = 768;
    src = (m == 0) ? wq : (m == 1) ? wk : (m == 2) ? wv : wo;
    dst = (m < 3) ? wqkvT + (size_t)m * 768 * 768 : woT;
    if (m == 0) scl = 0.125f;
  } else if (id < 1152) {
    int t = id - 576;
    kt = (t / 48) * 64; nt = (t % 48) * 64; K = 768; N = 3072;
    src = w1; dst = w1T;
  } else {
    int t = id - 1152;
    kt = (t / 12) * 64; nt = (t % 12) * 64; K = 3072; N = 768;
    src = w2; dst = w2T;
  }
  int r = tid >> 2, c = (tid & 3) * 16;
  const float* s = src + (size_t)(kt + r) * N + nt + c;
  bf16x8 t0, t1;
#pragma unroll
  for (int j = 0; j < 8; j++) {
    t0[j] = (bf16_t)(s[j] * scl);
    t1[j] = (bf16_t)(s[8 + j] * scl);
  }
  *(bf16x8*)&tile[r][c] = t0;
  *(bf16x8*)&tile[r][c + 8] = t1;
  __syncthreads();
  bf16_t* d = dst + (size_t)(nt + r) * K + kt + c;
  bf16x8 o0, o1;
#pragma unroll
  for (int j = 0; j < 8; j++) { o0[j] = tile[c + j][r]; o1[j] = tile[c + 8 + j][r]; }
  *(bf16x8*)d = o0;
  *(bf16x8*)(d + 8) = o1;
}

// ---------------- 128x128 bf16 MFMA GEMM, BK=64, XOR-swizzled LDS.
// NITER templated: K-loop fully unrolls via static_for; constexpr global
// displacements off hoisted base pointers; builtin offset stays 0 (R12
// lesson: the instruction offset also displaces the LDS destination).
// epi: 0 bf16 (V-tiles of QKV redirected transposed into vtout);
//      1 bias+GELU bf16; 2 bias+resid fp32; 3 bf16 partial +z*M*N.
template <int NITER>
__global__ __launch_bounds__(256) void k_gemm128(
    const bf16_t* __restrict__ A, const bf16_t* __restrict__ Bt,
    int M, int N, int K, int epi,
    float* __restrict__ outf, bf16_t* __restrict__ outb,
    const float* __restrict__ bias, const float* __restrict__ resid,
    bf16_t* __restrict__ vtout) {
  __shared__ bf16_t As[128 * 64];
  __shared__ bf16_t Bs[128 * 64];
  int tid = threadIdx.x;
  int wave = tid >> 6, lane = tid & 63;
  int m0 = blockIdx.y * 128, n0 = blockIdx.x * 128;
  int kOff = blockIdx.z * (NITER * 64);
  int wm = (wave >> 1) * 64, wn = (wave & 1) * 64;
  int lm = lane & 15, quad = lane >> 4;

  int srow = wave * 32 + (lane >> 3);
  int scol = (((lane & 7) ^ ((lane >> 3) & 7)) * 8);
  const bf16_t* Ap[4];
  const bf16_t* Bp[4];
  bf16_t* ldsA[4];
  bf16_t* ldsB[4];
#pragma unroll
  for (int j = 0; j < 4; j++) {
    Ap[j] = A + (size_t)(m0 + srow) * K + kOff + scol + (size_t)j * 8 * K;
    Bp[j] = Bt + (size_t)(n0 + srow) * K + kOff + scol + (size_t)j * 8 * K;
    ldsA[j] = &As[(wave * 32 + j * 8) * 64];
    ldsB[j] = &Bs[(wave * 32 + j * 8) * 64];
  }

  int aOff[2][4], bOff[2][4];
#pragma unroll
  for (int c = 0; c < 2; c++) {
    int g = ((c * 4 + quad) ^ (lm & 7)) * 8;
#pragma unroll
    for (int i = 0; i < 4; i++) {
      aOff[c][i] = (wm + i * 16 + lm) * 64 + g;
      bOff[c][i] = (wn + i * 16 + lm) * 64 + g;
    }
  }

  f32x4 acc[4][4];
#pragma unroll
  for (int i = 0; i < 4; i++)
#pragma unroll
    for (int j = 0; j < 4; j++) acc[i][j] = (f32x4){0.f, 0.f, 0.f, 0.f};

  static_for<NITER>([&](auto kc) {
    constexpr int k = decltype(kc)::value;
    __syncthreads();
#pragma unroll
    for (int j = 0; j < 4; j++) {
      __builtin_amdgcn_global_load_lds(
          (const __attribute__((address_space(1))) void*)(Ap[j] + k * 64),
          (__attribute__((address_space(3))) void*)ldsA[j], 16, 0, 0);
      __builtin_amdgcn_global_load_lds(
          (const __attribute__((address_space(1))) void*)(Bp[j] + k * 64),
          (__attribute__((address_space(3))) void*)ldsB[j], 16, 0, 0);
    }
    __syncthreads();
#pragma unroll
    for (int c = 0; c < 2; c++) {
      bf16x8 af[4], bfr[4];
#pragma unroll
      for (int i = 0; i < 4; i++) {
        af[i] = *(const bf16x8*)&As[aOff[c][i]];
        bfr[i] = *(const bf16x8*)&Bs[bOff[c][i]];
      }
#pragma unroll
      for (int i = 0; i < 4; i++)
#pragma unroll
        for (int j = 0; j < 4; j++)
          acc[i][j] = __builtin_amdgcn_mfma_f32_16x16x32_bf16(af[i], bfr[j], acc[i][j], 0, 0, 0);
    }
  });

  size_t pbase = (size_t)blockIdx.z * M * N;
  bool vtile = (epi == 0) && (n0 >= 2 * EE);
#pragma unroll
  for (int i = 0; i < 4; i++) {
#pragma unroll
    for (int j = 0; j < 4; j++) {
      int col = n0 + wn + j * 16 + lm;
      if (vtile) {
        int hv = (col - 2 * EE) >> 6, d = (col - 2 * EE) & 63;
        int row0 = m0 + wm + i * 16 + quad * 4;
        int bb = row0 >> 11, t0 = row0 & (TB - 1);
        bf16x4 v4;
#pragma unroll
        for (int r = 0; r < 4; r++) v4[r] = (bf16_t)acc[i][j][r];
        *(bf16x4*)&vtout[((size_t)(bb * HH + hv) * 64 + d) * TB + t0] = v4;
        continue;
      }
#pragma unroll
      for (int r = 0; r < 4; r++) {
        int row = m0 + wm + i * 16 + quad * 4 + r;
        size_t o = (size_t)row * N + col;
        float c = acc[i][j][r];
        if (epi == 0) {
          outb[o] = (bf16_t)c;
        } else if (epi == 1) {
          float xg = c + bias[col];
          float u2 = xg * 1.5957691216057308f + xg * xg * xg * 0.07135481627561393f;
          float t = 1.f - 2.f / (__expf(u2) + 1.f);  // tanh(u2/2), inf-safe
          outb[o] = (bf16_t)(0.5f * xg * (1.f + t));
        } else if (epi == 2) {
          outf[o] = c + bias[col] + resid[o];
        } else {
          outb[pbase + o] = (bf16_t)c;
        }
      }
    }
  }
}

// ---------------- attn-out reduce (2 partials) + bias + resid -> x1, fused LN2 -> h2
__global__ __launch_bounds__(256) void k_reduce_ln2(
    const bf16_t* __restrict__ p, const float* __restrict__ bo_,
    const float* __restrict__ x, const float* __restrict__ sc,
    const float* __restrict__ sh, float* __restrict__ x1,
    bf16_t* __restrict__ h2) {
  int wave = threadIdx.x >> 6, lane = threadIdx.x & 63;
  int row = blockIdx.x * 4 + wave;
  const bf16_t* p0 = p + (size_t)row * EE;
  const bf16_t* p1 = p0 + (size_t)MM * EE;
  const float* xr = x + (size_t)row * EE;
  float v[12];
  float s = 0.f, sq = 0.f;
#pragma unroll
  for (int i = 0; i < 12; i++) {
    int e = lane + 64 * i;
    float t = (float)p0[e] + (float)p1[e] + bo_[e] + xr[e];
    v[i] = t; s += t; sq += t * t;
  }
#pragma unroll
  for (int off = 1; off < 64; off <<= 1) {
    s += __shfl_xor(s, off);
    sq += __shfl_xor(sq, off);
  }
  float mean = s * (1.f / EE);
  float var = (sq - (float)EE * mean * mean) * (1.f / (EE - 1));
  float rstd = rsqrtf(var + 1e-5f);
  float* x1r = x1 + (size_t)row * EE;
  bf16_t* h2r = h2 + (size_t)row * EE;
#pragma unroll
  for (int i = 0; i < 12; i++) {
    int e = lane + 64 * i;
    x1r[e] = v[i];
    h2r[e] = (bf16_t)(sc[e] * (v[i] - mean) * rstd + sh[e]);
  }
}

// ---------------- MLP2 reduce (4 partials) + bias + resid -> out (fp32)
__global__ __launch_bounds__(256) void k_reduce_out(
    const bf16_t* __restrict__ p, const float* __restrict__ b2,
    const float* __restrict__ x1, float* __restrict__ out) {
  size_t e = ((size_t)blockIdx.x * 256 + threadIdx.x) * 8;
  bf16x8 a0 = *(const bf16x8*)(p + e);
  bf16x8 a1 = *(const bf16x8*)(p + (size_t)MM * EE + e);
  bf16x8 a2 = *(const bf16x8*)(p + (size_t)2 * MM * EE + e);
  bf16x8 a3 = *(const bf16x8*)(p + (size_t)3 * MM * EE + e);
  int col = (int)(e % EE);
#pragma unroll
  for (int j = 0; j < 8; j++) {
    out[e + j] = (float)a0[j] + (float)a1[j] + (float)a2[j] + (float)a3[j] +
                 b2[col + j] + x1[e + j];
  }
}

// ---------------- MFMA flash attention, causal, NO-MAX softmax, kv-split.
__global__ __launch_bounds__(256) void k_attn_mfma(const bf16_t* __restrict__ qkv,
                                                   const bf16_t* __restrict__ vt,
                                                   bf16_t* __restrict__ opart,
                                                   float* __restrict__ lpart) {
  __shared__ bf16_t Qs[64][72];
  __shared__ bf16_t Ks[64][72];
  __shared__ bf16_t Vt[64][72];
  __shared__ bf16_t Ps[4][16][72];

  int bh = blockIdx.x;
  int y = blockIdx.y;
  int qt, c, nsplit;
  if (y < 32)      { qt = 24 + (y >> 2); c = y & 3; nsplit = 4; }
  else if (y < 56) { int z = y - 32; qt = 16 + z / 3; c = z - (z / 3) * 3; nsplit = 3; }
  else if (y < 72) { int z = y - 56; qt = 8 + (z >> 1); c = z & 1; nsplit = 2; }
  else             { qt = y - 72; c = 0; nsplit = 1; }
  int ntiles = qt + 1;
  int len = (ntiles + nsplit - 1) / nsplit;
  int k0t = c * len;
  int k1t = k0t + len < ntiles ? k0t + len : ntiles;

  int b = bh / HH, h = bh - b * HH;
  int q0 = qt * 64;
  int tid = threadIdx.x;
  int wave = tid >> 6, lane = tid & 63;
  int lm = lane & 15, quad = lane >> 4;
  int sr = tid >> 2, sc = (tid & 3) * 16;
  const bf16_t* vt_bh = vt + (size_t)bh * 64 * TB;

  {
    const bf16_t* src = qkv + (size_t)(b * TB + q0 + sr) * E3 + h * 64 + sc;
    *(bf16x8*)(&Qs[sr][sc]) = *(const bf16x8*)src;
    *(bf16x8*)(&Qs[sr][sc + 8]) = *(const bf16x8*)(src + 8);
  }
  __syncthreads();
  bf16x8 qf0 = *(const bf16x8*)(&Qs[wave * 16 + lm][quad * 8]);
  bf16x8 qf1 = *(const bf16x8*)(&Qs[wave * 16 + lm][32 + quad * 8]);

  f32x4 o_acc[4];
#pragma unroll
  for (int nt = 0; nt < 4; nt++) o_acc[nt] = (f32x4){0.f, 0.f, 0.f, 0.f};
  float l = 0.f;

  for (int kt = k0t; kt < k1t; kt++) {
    __syncthreads();
    {
      const bf16_t* ksrc = qkv + (size_t)(b * TB + kt * 64 + sr) * E3 + EE + h * 64 + sc;
      *(bf16x8*)(&Ks[sr][sc]) = *(const bf16x8*)ksrc;
      *(bf16x8*)(&Ks[sr][sc + 8]) = *(const bf16x8*)(ksrc + 8);
      const bf16_t* vsrc = vt_bh + (size_t)sr * TB + kt * 64 + sc;
      *(bf16x8*)(&Vt[sr][sc]) = *(const bf16x8*)vsrc;
      *(bf16x8*)(&Vt[sr][sc + 8]) = *(const bf16x8*)(vsrc + 8);
    }
    __syncthreads();

    f32x4 st[4];
#pragma unroll
    for (int nt = 0; nt < 4; nt++) {
      st[nt] = (f32x4){0.f, 0.f, 0.f, 0.f};
      bf16x8 kf0 = *(const bf16x8*)(&Ks[nt * 16 + lm][quad * 8]);
      bf16x8 kf1 = *(const bf16x8*)(&Ks[nt * 16 + lm][32 + quad * 8]);
      st[nt] = __builtin_amdgcn_mfma_f32_16x16x32_bf16(kf0, qf0, st[nt], 0, 0, 0);
      st[nt] = __builtin_amdgcn_mfma_f32_16x16x32_bf16(kf1, qf1, st[nt], 0, 0, 0);
    }
    if (kt == qt) {
#pragma unroll
      for (int nt = 0; nt < 4; nt++)
#pragma unroll
        for (int r = 0; r < 4; r++)
          if (nt * 16 + quad * 4 + r > wave * 16 + lm) st[nt][r] = -1e30f;
    }

#pragma unroll
    for (int nt = 0; nt < 4; nt++) {
      bf16x4 pk;
#pragma unroll
      for (int r = 0; r < 4; r++) {
        float p = __expf(st[nt][r]);
        pk[r] = (bf16_t)p;
        l += p;
      }
      *(bf16x4*)(&Ps[wave][lm][nt * 16 + quad * 4]) = pk;
    }

    bf16x8 pf0 = *(const bf16x8*)(&Ps[wave][lm][quad * 8]);
    bf16x8 pf1 = *(const bf16x8*)(&Ps[wave][lm][32 + quad * 8]);
#pragma unroll
    for (int nt = 0; nt < 4; nt++) {
      bf16x8 vf0 = *(const bf16x8*)(&Vt[nt * 16 + lm][quad * 8]);
      bf16x8 vf1 = *(const bf16x8*)(&Vt[nt * 16 + lm][32 + quad * 8]);
      o_acc[nt] = __builtin_amdgcn_mfma_f32_16x16x32_bf16(pf0, vf0, o_acc[nt], 0, 0, 0);
      o_acc[nt] = __builtin_amdgcn_mfma_f32_16x16x32_bf16(pf1, vf1, o_acc[nt], 0, 0, 0);
    }
  }

  l += __shfl_xor(l, 16);
  l += __shfl_xor(l, 32);
  size_t slot = (size_t)(bh * 32 + qt) * 4 + c;
  if (quad == 0) lpart[slot * 64 + wave * 16 + lm] = l;
  bf16_t* ob = opart + slot * 4096;
#pragma unroll
  for (int nt = 0; nt < 4; nt++)
#pragma unroll
    for (int r = 0; r < 4; r++)
      ob[(wave * 16 + quad * 4 + r) * 64 + nt * 16 + lm] = (bf16_t)o_acc[nt][r];
}

// ---------------- merge attn partials: ctx = (sum_c O_c) / (sum_c l_c)
__global__ __launch_bounds__(256) void k_attn_reduce(
    const bf16_t* __restrict__ opart, const float* __restrict__ lpart,
    bf16_t* __restrict__ ctx) {
  int bh = blockIdx.x, qt = blockIdx.y;
  int b = bh / HH, h = bh - b * HH;
  int nsplit = qt >= 24 ? 4 : qt >= 16 ? 3 : qt >= 8 ? 2 : 1;
  int tid = threadIdx.x;
  int q = tid >> 2, dc = (tid & 3) * 16;
  size_t slot0 = (size_t)(bh * 32 + qt) * 4;
  float o[16];
#pragma unroll
  for (int j = 0; j < 16; j++) o[j] = 0.f;
  float lsum = 0.f;
  for (int c = 0; c < nsplit; c++) {
    const bf16_t* p = opart + (slot0 + c) * 4096 + q * 64 + dc;
    bf16x8 u0 = *(const bf16x8*)p;
    bf16x8 u1 = *(const bf16x8*)(p + 8);
#pragma unroll
    for (int j = 0; j < 8; j++) { o[j] += (float)u0[j]; o[8 + j] += (float)u1[j]; }
    lsum += lpart[(slot0 + c) * 64 + q];
  }
  float inv = 1.f / lsum;
  bf16_t* dst = ctx + (size_t)(b * TB + qt * 64 + q) * EE + h * 64 + dc;
  bf16x8 d0, d1;
#pragma unroll
  for (int j = 0; j < 8; j++) { d0[j] = (bf16_t)(o[j] * inv); d1[j] = (bf16_t)(o[8 + j] * inv); }
  *(bf16x8*)dst = d0;
  *(bf16x8*)(dst + 8) = d1;
}

extern "C" void kernel_launch(void* const* d_in, const int* in_sizes, int n_in,
                              void* d_out, int out_size, void* d_ws, size_t ws_size,
                              hipStream_t stream) {
  const float* x    = (const float*)d_in[0];
  const float* wq   = (const float*)d_in[1];
  const float* wk   = (const float*)d_in[2];
  const float* wv   = (const float*)d_in[3];
  const float* wo   = (const float*)d_in[4];
  const float* bo   = (const float*)d_in[5];
  const float* ln1s = (const float*)d_in[6];
  const float* ln1b = (const float*)d_in[7];
  const float* ln2s = (const float*)d_in[8];
  const float* ln2b = (const float*)d_in[9];
  const float* w1   = (const float*)d_in[10];
  const float* b1   = (const float*)d_in[11];
  const float* w2   = (const float*)d_in[12];
  const float* b2   = (const float*)d_in[13];
  float* out = (float*)d_out;

  char* ws = (char*)d_ws;
  size_t off = 0;
  auto alloc = [&](size_t bytes) {
    char* p = ws + off;
    off += (bytes + 255) & ~(size_t)255;
    return p;
  };
  float*  x1    = (float*) alloc((size_t)MM * EE * 4);   // post-attn residual
  bf16_t* w1T   = (bf16_t*)alloc((size_t)E4 * EE * 2);
  bf16_t* w2T   = (bf16_t*)alloc((size_t)EE * E4 * 2);
  bf16_t* woT   = (bf16_t*)alloc((size_t)EE * EE * 2);
  bf16_t* wqkvT = (bf16_t*)alloc((size_t)E3 * EE * 2);
  bf16_t* hbf   = (bf16_t*)alloc((size_t)MM * EE * 2);   // ln1 out; reused as ctx
  bf16_t* h2    = (bf16_t*)alloc((size_t)MM * EE * 2);   // ln2 out
  bf16_t* vtb   = (bf16_t*)alloc((size_t)BB * HH * 64 * TB * 2);  // V^T
  bf16_t* part  = (bf16_t*)alloc((size_t)4 * MM * EE * 2);        // split-K partials
  bf16_t* opart = (bf16_t*)alloc((size_t)BB * HH * 32 * 4 * 4096 * 2);  // attn O partials
  float*  lpart = (float*) alloc((size_t)BB * HH * 32 * 4 * 64 * 4);    // attn l partials
  bf16_t* qkv   = (bf16_t*)alloc((size_t)MM * E3 * 2);   // LAST: hmid overlays +6.3MB
  bf16_t* hmid  = qkv;  // MLP mid (4096 x 3072)

  // weight transposes (wq pre-scaled 0.125) + LN1 in one dispatch
  k_prep<<<2752, 256, 0, stream>>>(wq, wk, wv, wo, w1, w2,
                                   wqkvT, woT, w1T, w2T, x, ln1s, ln1b, hbf);
  // fused QKV projection (K=768 -> 12 iters); V-tiles written transposed into vtb
  k_gemm128<12><<<dim3(E3 / 128, MM / 128), 256, 0, stream>>>(
      hbf, wqkvT, MM, E3, EE, 0, nullptr, qkv, nullptr, nullptr, vtb);
  // attention: kv-split partials (1920 balanced blocks), then merge
  k_attn_mfma<<<dim3(BB * HH, 80), 256, 0, stream>>>(qkv, vtb, opart, lpart);
  k_attn_reduce<<<dim3(BB * HH, TB / 64), 256, 0, stream>>>(opart, lpart, hbf);
  // output projection: split-K x2 (kLen=384 -> 6 iters) -> bf16 partials
  k_gemm128<6><<<dim3(EE / 128, MM / 128, 2), 256, 0, stream>>>(
      hbf, woT, MM, EE, EE, 3, nullptr, part, nullptr, nullptr, nullptr);
  // reduce 2 partials + bias + resid -> x1, fused LN2 -> h2
  k_reduce_ln2<<<MM / 4, 256, 0, stream>>>(part, bo, x, ln2s, ln2b, x1, h2);
  // MLP1 + bias + gelu (K=768 -> 12 iters)
  k_gemm128<12><<<dim3(E4 / 128, MM / 128), 256, 0, stream>>>(
      h2, w1T, MM, E4, EE, 1, nullptr, hmid, b1, nullptr, nullptr);
  // MLP2: split-K x4 (kLen=768 -> 12 iters) -> bf16 partials
  k_gemm128<12><<<dim3(EE / 128, MM / 128, 4), 256, 0, stream>>>(
      hmid, w2T, MM, EE, E4, 3, nullptr, part, nullptr, nullptr, nullptr);
  // reduce + bias + resid -> out
  k_reduce_out<<<(MM * EE / 8 + 255) / 256, 256, 0, stream>>>(part, b2, x1, out);
}